// Round 1
// baseline (492.566 us; speedup 1.0000x reference)
//
#include <hip/hip_runtime.h>

#define T_TOK 512
#define HID   2048
#define NEXP  16
#define IDIM  1024
#define KC    32

// ---------------- router: logits -> softmax -> top2 -> renorm + expert lists ----------------
__global__ __launch_bounds__(256) void router_kernel(
    const float* __restrict__ x, const float* __restrict__ rw,
    int* __restrict__ cnt, int* __restrict__ tok,
    int* __restrict__ rowid, float* __restrict__ wt)
{
    int t = blockIdx.x;
    int tid = threadIdx.x;
    const float* xr = x + (size_t)t * HID;

    float acc[NEXP];
#pragma unroll
    for (int e = 0; e < NEXP; ++e) acc[e] = 0.f;

    for (int k = tid; k < HID; k += 256) {
        float xv = xr[k];
#pragma unroll
        for (int e = 0; e < NEXP; ++e) acc[e] += xv * rw[e * HID + k];
    }

    __shared__ float red[4][NEXP];
    int lane = tid & 63, wv = tid >> 6;
#pragma unroll
    for (int e = 0; e < NEXP; ++e) {
        float v = acc[e];
#pragma unroll
        for (int off = 32; off > 0; off >>= 1) v += __shfl_down(v, off);
        if (lane == 0) red[wv][e] = v;
    }
    __syncthreads();

    if (tid == 0) {
        float l[NEXP];
        float mx = -1e30f;
#pragma unroll
        for (int e = 0; e < NEXP; ++e) {
            l[e] = red[0][e] + red[1][e] + red[2][e] + red[3][e];
            mx = fmaxf(mx, l[e]);
        }
        float s = 0.f;
#pragma unroll
        for (int e = 0; e < NEXP; ++e) { l[e] = __expf(l[e] - mx); s += l[e]; }
        float inv_s = 1.f / s;
        int i0 = 0; float v0 = -1.f;
        int i1 = 0; float v1 = -2.f;
#pragma unroll
        for (int e = 0; e < NEXP; ++e) {
            float p = l[e] * inv_s;
            if (p > v0)      { v1 = v0; i1 = i0; v0 = p; i0 = e; }
            else if (p > v1) { v1 = p; i1 = e; }
        }
        float inv = 1.f / (v0 + v1);
        int p0 = atomicAdd(&cnt[i0], 1);
        tok[i0 * T_TOK + p0] = t; rowid[i0 * T_TOK + p0] = 2 * t;     wt[i0 * T_TOK + p0] = v0 * inv;
        int p1 = atomicAdd(&cnt[i1], 1);
        tok[i1 * T_TOK + p1] = t; rowid[i1 * T_TOK + p1] = 2 * t + 1; wt[i1 * T_TOK + p1] = v1 * inv;
    }
}

// ---------------- gemm1: h[row] = wt * silu(x@Wg) * (x@Wu), gathered per expert ----------------
__global__ __launch_bounds__(256) void gemm1_kernel(
    const float* __restrict__ x, const float* __restrict__ w13,
    const int* __restrict__ cnt, const int* __restrict__ tok,
    const int* __restrict__ rowid, const float* __restrict__ wt,
    float* __restrict__ h)
{
    int e = blockIdx.z;
    int n = cnt[e];
    int t0 = blockIdx.y * 64;
    if (t0 >= n) return;
    int c0 = blockIdx.x * 64;          // tile base within I
    int nt = min(64, n - t0);
    int tid = threadIdx.x;

    __shared__ float Xs[KC][64 + 1];
    __shared__ float Wg[KC][64 + 1];
    __shared__ float Wu[KC][64 + 1];
    __shared__ int   tks[64];
    __shared__ int   rws[64];
    __shared__ float wts[64];

    if (tid < 64) {
        int idx = t0 + min(tid, nt - 1);
        tks[tid] = tok[e * T_TOK + idx];
        rws[tid] = rowid[e * T_TOK + idx];
        wts[tid] = wt[e * T_TOK + idx];
    }
    __syncthreads();

    const float* wbase = w13 + (size_t)e * HID * (2 * IDIM);

    float accG[4][4], accU[4][4];
#pragma unroll
    for (int i = 0; i < 4; ++i)
#pragma unroll
        for (int j = 0; j < 4; ++j) { accG[i][j] = 0.f; accU[i][j] = 0.f; }

    int tx = tid & 15, ty = tid >> 4;

    for (int kk = 0; kk < HID; kk += KC) {
        // stage X tile: [KC][64 tokens]
#pragma unroll
        for (int j = 0; j < 8; ++j) {
            int idx = tid + j * 256;
            int tk = idx >> 5;         // token within tile
            int k  = idx & 31;
            Xs[k][tk] = x[(size_t)tks[tk] * HID + kk + k];
        }
        // stage W tiles: [KC][64 cols] for gate and up halves
#pragma unroll
        for (int j = 0; j < 8; ++j) {
            int idx = tid + j * 256;
            int k = idx >> 6;
            int c = idx & 63;
            const float* wp = wbase + (size_t)(kk + k) * (2 * IDIM) + c0 + c;
            Wg[k][c] = wp[0];
            Wu[k][c] = wp[IDIM];
        }
        __syncthreads();
#pragma unroll
        for (int k = 0; k < KC; ++k) {
            float xv[4], gv[4], uv[4];
#pragma unroll
            for (int i = 0; i < 4; ++i) xv[i] = Xs[k][ty * 4 + i];
#pragma unroll
            for (int j = 0; j < 4; ++j) { gv[j] = Wg[k][tx * 4 + j]; uv[j] = Wu[k][tx * 4 + j]; }
#pragma unroll
            for (int i = 0; i < 4; ++i)
#pragma unroll
                for (int j = 0; j < 4; ++j) {
                    accG[i][j] += xv[i] * gv[j];
                    accU[i][j] += xv[i] * uv[j];
                }
        }
        __syncthreads();
    }

#pragma unroll
    for (int i = 0; i < 4; ++i) {
        int r = ty * 4 + i;
        if (r < nt) {
            int hr = rws[r];
            float w = wts[r];
#pragma unroll
            for (int j = 0; j < 4; ++j) {
                float g = accG[i][j], u = accU[i][j];
                float sg = g / (1.f + __expf(-g));
                h[(size_t)hr * IDIM + c0 + tx * 4 + j] = w * (sg * u);
            }
        }
    }
}

// ---------------- gemm2: out[t] += h[row] @ w2[e], atomic scatter-add ----------------
__global__ __launch_bounds__(256) void gemm2_kernel(
    const float* __restrict__ h, const float* __restrict__ w2,
    const int* __restrict__ cnt, const int* __restrict__ tok,
    const int* __restrict__ rowid,
    float* __restrict__ out)
{
    int e = blockIdx.z;
    int n = cnt[e];
    int t0 = blockIdx.y * 64;
    if (t0 >= n) return;
    int c0 = blockIdx.x * 64;          // tile base within H
    int nt = min(64, n - t0);
    int tid = threadIdx.x;

    __shared__ float Hs[KC][64 + 1];
    __shared__ float Ws[KC][64 + 1];
    __shared__ int tks[64];
    __shared__ int rws[64];

    if (tid < 64) {
        int idx = t0 + min(tid, nt - 1);
        tks[tid] = tok[e * T_TOK + idx];
        rws[tid] = rowid[e * T_TOK + idx];
    }
    __syncthreads();

    const float* wbase = w2 + (size_t)e * IDIM * HID;

    float acc[4][4];
#pragma unroll
    for (int i = 0; i < 4; ++i)
#pragma unroll
        for (int j = 0; j < 4; ++j) acc[i][j] = 0.f;

    int tx = tid & 15, ty = tid >> 4;

    for (int kk = 0; kk < IDIM; kk += KC) {
#pragma unroll
        for (int j = 0; j < 8; ++j) {
            int idx = tid + j * 256;
            int r = idx >> 5;
            int k = idx & 31;
            Hs[k][r] = h[(size_t)rws[r] * IDIM + kk + k];
        }
#pragma unroll
        for (int j = 0; j < 8; ++j) {
            int idx = tid + j * 256;
            int k = idx >> 6;
            int c = idx & 63;
            Ws[k][c] = wbase[(size_t)(kk + k) * HID + c0 + c];
        }
        __syncthreads();
#pragma unroll
        for (int k = 0; k < KC; ++k) {
            float hv[4], wv[4];
#pragma unroll
            for (int i = 0; i < 4; ++i) hv[i] = Hs[k][ty * 4 + i];
#pragma unroll
            for (int j = 0; j < 4; ++j) wv[j] = Ws[k][tx * 4 + j];
#pragma unroll
            for (int i = 0; i < 4; ++i)
#pragma unroll
                for (int j = 0; j < 4; ++j)
                    acc[i][j] += hv[i] * wv[j];
        }
        __syncthreads();
    }

#pragma unroll
    for (int i = 0; i < 4; ++i) {
        int r = ty * 4 + i;
        if (r < nt) {
            int t = tks[r];
#pragma unroll
            for (int j = 0; j < 4; ++j)
                atomicAdd(&out[(size_t)t * HID + c0 + tx * 4 + j], acc[i][j]);
        }
    }
}

extern "C" void kernel_launch(void* const* d_in, const int* in_sizes, int n_in,
                              void* d_out, int out_size, void* d_ws, size_t ws_size,
                              hipStream_t stream) {
    const float* x   = (const float*)d_in[0];   // [T, H]
    const float* rw  = (const float*)d_in[1];   // [E, H]
    const float* w13 = (const float*)d_in[2];   // [E, H, 2I]
    const float* w2  = (const float*)d_in[3];   // [E, I, H]
    float* out = (float*)d_out;                 // [T, H]

    int* cnt   = (int*)d_ws;                    // 64 ints (16 used)
    int* tok   = cnt + 64;                      // [E*T]
    int* rowid = tok + NEXP * T_TOK;            // [E*T]
    float* wt  = (float*)(rowid + NEXP * T_TOK);// [E*T]
    float* h   = wt + NEXP * T_TOK;             // [2T, I] = 4 MB

    hipMemsetAsync(out, 0, (size_t)T_TOK * HID * sizeof(float), stream);
    hipMemsetAsync(cnt, 0, 64 * sizeof(int), stream);

    router_kernel<<<T_TOK, 256, 0, stream>>>(x, rw, cnt, tok, rowid, wt);
    gemm1_kernel<<<dim3(IDIM / 64, T_TOK / 64, NEXP), 256, 0, stream>>>(x, w13, cnt, tok, rowid, wt, h);
    gemm2_kernel<<<dim3(HID / 64, T_TOK / 64, NEXP), 256, 0, stream>>>(h, w2, cnt, tok, rowid, out);
}

// Round 2
// 199.535 us; speedup vs baseline: 2.4686x; 2.4686x over previous
//
#include <hip/hip_runtime.h>

#define T_TOK 512
#define HID   2048
#define NEXP  16
#define IDIM  1024
#define KC    64

typedef __attribute__((ext_vector_type(8))) short bf16x8;
typedef __attribute__((ext_vector_type(4))) float f32x4;
typedef __attribute__((ext_vector_type(4))) float float4v;

__device__ __forceinline__ unsigned short f2bf(float f) {
    union { float f; unsigned u; } v; v.f = f;
    return (unsigned short)((v.u + 0x7FFFu + ((v.u >> 16) & 1u)) >> 16);
}

__device__ __forceinline__ bf16x8 pack8(const float* s) {
    bf16x8 r;
#pragma unroll
    for (int i = 0; i < 8; ++i) r[i] = (short)f2bf(s[i]);
    return r;
}

// ---------------- router: logits -> softmax -> top2 -> renorm + expert lists ----------------
__global__ __launch_bounds__(256) void router_kernel(
    const float* __restrict__ x, const float* __restrict__ rw,
    int* __restrict__ cnt, int* __restrict__ tok,
    int* __restrict__ rowid, float* __restrict__ wt)
{
    int t = blockIdx.x;
    int tid = threadIdx.x;
    const float* xr = x + (size_t)t * HID;

    float acc[NEXP];
#pragma unroll
    for (int e = 0; e < NEXP; ++e) acc[e] = 0.f;

    for (int k = tid; k < HID; k += 256) {
        float xv = xr[k];
#pragma unroll
        for (int e = 0; e < NEXP; ++e) acc[e] += xv * rw[e * HID + k];
    }

    __shared__ float red[4][NEXP];
    int lane = tid & 63, wv = tid >> 6;
#pragma unroll
    for (int e = 0; e < NEXP; ++e) {
        float v = acc[e];
#pragma unroll
        for (int off = 32; off > 0; off >>= 1) v += __shfl_down(v, off);
        if (lane == 0) red[wv][e] = v;
    }
    __syncthreads();

    if (tid == 0) {
        float l[NEXP];
        float mx = -1e30f;
#pragma unroll
        for (int e = 0; e < NEXP; ++e) {
            l[e] = red[0][e] + red[1][e] + red[2][e] + red[3][e];
            mx = fmaxf(mx, l[e]);
        }
        float s = 0.f;
#pragma unroll
        for (int e = 0; e < NEXP; ++e) { l[e] = __expf(l[e] - mx); s += l[e]; }
        float inv_s = 1.f / s;
        int i0 = 0; float v0 = -1.f;
        int i1 = 0; float v1 = -2.f;
#pragma unroll
        for (int e = 0; e < NEXP; ++e) {
            float p = l[e] * inv_s;
            if (p > v0)      { v1 = v0; i1 = i0; v0 = p; i0 = e; }
            else if (p > v1) { v1 = p; i1 = e; }
        }
        float inv = 1.f / (v0 + v1);
        int p0 = atomicAdd(&cnt[i0], 1);
        tok[i0 * T_TOK + p0] = t; rowid[i0 * T_TOK + p0] = 2 * t;     wt[i0 * T_TOK + p0] = v0 * inv;
        int p1 = atomicAdd(&cnt[i1], 1);
        tok[i1 * T_TOK + p1] = t; rowid[i1 * T_TOK + p1] = 2 * t + 1; wt[i1 * T_TOK + p1] = v1 * inv;
    }
}

// ---------------- gemm1: h[row] = wt * silu(x@Wg) * (x@Wu), MFMA bf16 ----------------
// block: 64 tokens x 64 h-cols (gate + up), 256 threads = 4 waves
__global__ __launch_bounds__(256) void gemm1_kernel(
    const float* __restrict__ x, const float* __restrict__ w13,
    const int* __restrict__ cnt, const int* __restrict__ tok,
    const int* __restrict__ rowid, const float* __restrict__ wt,
    unsigned short* __restrict__ h)
{
    int e = blockIdx.z;
    int n = cnt[e];
    int t0 = blockIdx.y * 64;
    if (t0 >= n) return;
    int c0 = blockIdx.x * 64;          // h-col base; gate col = c0+cc, up col = IDIM+c0+cc
    int nt = min(64, n - t0);
    int tid = threadIdx.x;

    __shared__ short Xs[64 * KC];      // [token][k] bf16, XOR-swizzled, 8 KB
    __shared__ short Ws[128 * KC];     // [wcol][k]: rows 0-63 gate, 64-127 up; 16 KB
    __shared__ int   tks[64];
    __shared__ int   rws[64];
    __shared__ float wts[64];

    if (tid < 64) {
        int idx = t0 + min(tid, nt - 1);
        tks[tid] = tok[e * T_TOK + idx];
        rws[tid] = rowid[e * T_TOK + idx];
        wts[tid] = wt[e * T_TOK + idx];
    }
    __syncthreads();

    const float* wbase = w13 + (size_t)e * HID * (2 * IDIM);

    // staging roles
    int xrow = tid >> 2, xq = tid & 3;                 // X: 4 threads per token row
    const float* xsrc = x + (size_t)tks[xrow] * HID + xq * 16;
    int cc = tid & 127, khalf = tid >> 7;              // W: thread <-> weight col, 2 k-halves
    int gcol = (cc < 64) ? (c0 + cc) : (IDIM + c0 + (cc - 64));
    const float* wsrc = wbase + (size_t)khalf * 32 * (2 * IDIM) + gcol;
    int wswz = (cc & 7) << 4;

    int wave = tid >> 6, lane = tid & 63;
    int lr = lane & 15, lh = lane >> 4;
    int swzA = (lr & 7) << 4;

    f32x4 accG[4], accU[4];
#pragma unroll
    for (int i = 0; i < 4; ++i) { accG[i] = (f32x4)0.f; accU[i] = (f32x4)0.f; }

    for (int kk = 0; kk < HID; kk += KC) {
        // ---- stage X tile (fp32 -> bf16) ----
#pragma unroll
        for (int f = 0; f < 2; ++f) {
            float4v a = *(const float4v*)(xsrc + kk + f * 8);
            float4v b = *(const float4v*)(xsrc + kk + f * 8 + 4);
            float tmp[8];
#pragma unroll
            for (int i = 0; i < 4; ++i) { tmp[i] = a[i]; tmp[4 + i] = b[i]; }
            int byte = (xrow * 128 + xq * 32 + f * 16) ^ ((xrow & 7) << 4);
            *(bf16x8*)((char*)Xs + byte) = pack8(tmp);
        }
        // ---- stage W tile (transpose [k][col] -> [col][k], fp32 -> bf16) ----
        float wreg[32];
#pragma unroll
        for (int j = 0; j < 32; ++j)
            wreg[j] = wsrc[(size_t)(kk + j) * (2 * IDIM)];
#pragma unroll
        for (int q = 0; q < 4; ++q) {
            int byte = (cc * 128 + khalf * 64 + q * 16) ^ wswz;
            *(bf16x8*)((char*)Ws + byte) = pack8(&wreg[q * 8]);
        }
        __syncthreads();
        // ---- MFMA ----
#pragma unroll
        for (int s = 0; s < 2; ++s) {
            int kb = (s * 32 + lh * 8) * 2;
            bf16x8 a = *(const bf16x8*)((char*)Xs + (((wave * 16 + lr) * 128 + kb) ^ swzA));
#pragma unroll
            for (int cf = 0; cf < 4; ++cf) {
                bf16x8 bg = *(const bf16x8*)((char*)Ws + (((cf * 16 + lr) * 128 + kb) ^ swzA));
                accG[cf] = __builtin_amdgcn_mfma_f32_16x16x32_bf16(a, bg, accG[cf], 0, 0, 0);
                bf16x8 bu = *(const bf16x8*)((char*)Ws + (((64 + cf * 16 + lr) * 128 + kb) ^ swzA));
                accU[cf] = __builtin_amdgcn_mfma_f32_16x16x32_bf16(a, bu, accU[cf], 0, 0, 0);
            }
        }
        __syncthreads();
    }

    // ---- epilogue: silu(g)*u * wt -> h (bf16) ----
#pragma unroll
    for (int cf = 0; cf < 4; ++cf) {
#pragma unroll
        for (int r = 0; r < 4; ++r) {
            int idx = wave * 16 + lh * 4 + r;
            if (idx < nt) {
                float g = accG[cf][r], u = accU[cf][r];
                float sg = g / (1.f + __expf(-g));
                float v = wts[idx] * sg * u;
                h[(size_t)rws[idx] * IDIM + c0 + cf * 16 + lr] = f2bf(v);
            }
        }
    }
}

// ---------------- gemm2: out[t] += h[row] @ w2[e], MFMA bf16, atomic scatter ----------------
// block: 64 rows x 128 out-cols, 256 threads = 4 waves
__global__ __launch_bounds__(256) void gemm2_kernel(
    const unsigned short* __restrict__ h, const float* __restrict__ w2,
    const int* __restrict__ cnt, const int* __restrict__ tok,
    const int* __restrict__ rowid,
    float* __restrict__ out)
{
    int e = blockIdx.z;
    int n = cnt[e];
    int t0 = blockIdx.y * 64;
    if (t0 >= n) return;
    int c0 = blockIdx.x * 128;
    int nt = min(64, n - t0);
    int tid = threadIdx.x;

    __shared__ short Hs[64 * KC];      // [row][k] bf16, swizzled
    __shared__ short Ws[128 * KC];     // [col][k] bf16, swizzled
    __shared__ int   tks[64];
    __shared__ int   rws[64];

    if (tid < 64) {
        int idx = t0 + min(tid, nt - 1);
        tks[tid] = tok[e * T_TOK + idx];
        rws[tid] = rowid[e * T_TOK + idx];
    }
    __syncthreads();

    const float* wbase = w2 + (size_t)e * IDIM * HID;

    int hrow = tid >> 2, hq = tid & 3;
    const unsigned short* hsrc = h + (size_t)rws[hrow] * IDIM + hq * 16;
    int hswz = (hrow & 7) << 4;
    int cc = tid & 127, khalf = tid >> 7;
    const float* wsrc = wbase + (size_t)khalf * 32 * HID + c0 + cc;
    int wswz = (cc & 7) << 4;

    int wave = tid >> 6, lane = tid & 63;
    int lr = lane & 15, lh = lane >> 4;
    int swzA = (lr & 7) << 4;

    f32x4 acc[8];
#pragma unroll
    for (int i = 0; i < 8; ++i) acc[i] = (f32x4)0.f;

    for (int kk = 0; kk < IDIM; kk += KC) {
        // ---- stage H tile (already bf16, direct copy) ----
        *(bf16x8*)((char*)Hs + ((hrow * 128 + hq * 32) ^ hswz)) =
            *(const bf16x8*)(hsrc + kk);
        *(bf16x8*)((char*)Hs + ((hrow * 128 + hq * 32 + 16) ^ hswz)) =
            *(const bf16x8*)(hsrc + kk + 8);
        // ---- stage W2 tile (transpose + cvt) ----
        float wreg[32];
#pragma unroll
        for (int j = 0; j < 32; ++j)
            wreg[j] = wsrc[(size_t)(kk + j) * HID];
#pragma unroll
        for (int q = 0; q < 4; ++q) {
            int byte = (cc * 128 + khalf * 64 + q * 16) ^ wswz;
            *(bf16x8*)((char*)Ws + byte) = pack8(&wreg[q * 8]);
        }
        __syncthreads();
        // ---- MFMA ----
#pragma unroll
        for (int s = 0; s < 2; ++s) {
            int kb = (s * 32 + lh * 8) * 2;
            bf16x8 a = *(const bf16x8*)((char*)Hs + (((wave * 16 + lr) * 128 + kb) ^ swzA));
#pragma unroll
            for (int cf = 0; cf < 8; ++cf) {
                bf16x8 b = *(const bf16x8*)((char*)Ws + (((cf * 16 + lr) * 128 + kb) ^ swzA));
                acc[cf] = __builtin_amdgcn_mfma_f32_16x16x32_bf16(a, b, acc[cf], 0, 0, 0);
            }
        }
        __syncthreads();
    }

#pragma unroll
    for (int cf = 0; cf < 8; ++cf) {
#pragma unroll
        for (int r = 0; r < 4; ++r) {
            int idx = wave * 16 + lh * 4 + r;
            if (idx < nt)
                atomicAdd(&out[(size_t)tks[idx] * HID + c0 + cf * 16 + lr], acc[cf][r]);
        }
    }
}

extern "C" void kernel_launch(void* const* d_in, const int* in_sizes, int n_in,
                              void* d_out, int out_size, void* d_ws, size_t ws_size,
                              hipStream_t stream) {
    const float* x   = (const float*)d_in[0];   // [T, H]
    const float* rw  = (const float*)d_in[1];   // [E, H]
    const float* w13 = (const float*)d_in[2];   // [E, H, 2I]
    const float* w2  = (const float*)d_in[3];   // [E, I, H]
    float* out = (float*)d_out;                 // [T, H]

    int* cnt   = (int*)d_ws;                    // 64 ints
    int* tok   = cnt + 64;                      // [E*T]
    int* rowid = tok + NEXP * T_TOK;            // [E*T]
    float* wt  = (float*)(rowid + NEXP * T_TOK);// [E*T]
    unsigned short* h = (unsigned short*)((char*)d_ws + 131072); // [2T, I] bf16 = 2 MB

    hipMemsetAsync(out, 0, (size_t)T_TOK * HID * sizeof(float), stream);
    hipMemsetAsync(cnt, 0, 64 * sizeof(int), stream);

    router_kernel<<<T_TOK, 256, 0, stream>>>(x, rw, cnt, tok, rowid, wt);
    gemm1_kernel<<<dim3(IDIM / 64, T_TOK / 64, NEXP), 256, 0, stream>>>(x, w13, cnt, tok, rowid, wt, h);
    gemm2_kernel<<<dim3(HID / 128, T_TOK / 64, NEXP), 256, 0, stream>>>(h, w2, cnt, tok, rowid, out);
}

// Round 3
// 174.017 us; speedup vs baseline: 2.8306x; 1.1466x over previous
//
#include <hip/hip_runtime.h>

#define T_TOK 512
#define HID   2048
#define NEXP  16
#define IDIM  1024
#define KC    64

typedef __attribute__((ext_vector_type(8))) short bf16x8;
typedef __attribute__((ext_vector_type(4))) float f32x4;
typedef __attribute__((ext_vector_type(4))) float float4v;

__device__ __forceinline__ unsigned short f2bf(float f) {
    union { float f; unsigned u; } v; v.f = f;
    return (unsigned short)((v.u + 0x7FFFu + ((v.u >> 16) & 1u)) >> 16);
}

__device__ __forceinline__ bf16x8 pack8(const float* s) {
    bf16x8 r;
#pragma unroll
    for (int i = 0; i < 8; ++i) r[i] = (short)f2bf(s[i]);
    return r;
}

// ---------------- router ----------------
__global__ __launch_bounds__(256) void router_kernel(
    const float* __restrict__ x, const float* __restrict__ rw,
    int* __restrict__ cnt, int* __restrict__ tok,
    int* __restrict__ rowid, float* __restrict__ wt)
{
    int t = blockIdx.x;
    int tid = threadIdx.x;
    const float* xr = x + (size_t)t * HID;

    float acc[NEXP];
#pragma unroll
    for (int e = 0; e < NEXP; ++e) acc[e] = 0.f;

    for (int k = tid; k < HID; k += 256) {
        float xv = xr[k];
#pragma unroll
        for (int e = 0; e < NEXP; ++e) acc[e] += xv * rw[e * HID + k];
    }

    __shared__ float red[4][NEXP];
    int lane = tid & 63, wv = tid >> 6;
#pragma unroll
    for (int e = 0; e < NEXP; ++e) {
        float v = acc[e];
#pragma unroll
        for (int off = 32; off > 0; off >>= 1) v += __shfl_down(v, off);
        if (lane == 0) red[wv][e] = v;
    }
    __syncthreads();

    if (tid == 0) {
        float l[NEXP];
        float mx = -1e30f;
#pragma unroll
        for (int e = 0; e < NEXP; ++e) {
            l[e] = red[0][e] + red[1][e] + red[2][e] + red[3][e];
            mx = fmaxf(mx, l[e]);
        }
        float s = 0.f;
#pragma unroll
        for (int e = 0; e < NEXP; ++e) { l[e] = __expf(l[e] - mx); s += l[e]; }
        float inv_s = 1.f / s;
        int i0 = 0; float v0 = -1.f;
        int i1 = 0; float v1 = -2.f;
#pragma unroll
        for (int e = 0; e < NEXP; ++e) {
            float p = l[e] * inv_s;
            if (p > v0)      { v1 = v0; i1 = i0; v0 = p; i0 = e; }
            else if (p > v1) { v1 = p; i1 = e; }
        }
        float inv = 1.f / (v0 + v1);
        int p0 = atomicAdd(&cnt[i0], 1);
        tok[i0 * T_TOK + p0] = t; rowid[i0 * T_TOK + p0] = 2 * t;     wt[i0 * T_TOK + p0] = v0 * inv;
        int p1 = atomicAdd(&cnt[i1], 1);
        tok[i1 * T_TOK + p1] = t; rowid[i1 * T_TOK + p1] = 2 * t + 1; wt[i1 * T_TOK + p1] = v1 * inv;
    }
}

// ---------------- gemm1: h[row] = wt * silu(x@Wg) * (x@Wu) ----------------
// 1-D grid of 512 blocks: e = bid>>5, x-tile = (bid>>1)&15, y-parity = bid&1.
__global__ __launch_bounds__(256) void gemm1_kernel(
    const float* __restrict__ x, const float* __restrict__ w13,
    const int* __restrict__ cnt, const int* __restrict__ tok,
    const int* __restrict__ rowid, const float* __restrict__ wt,
    unsigned short* __restrict__ h)
{
    int bid = blockIdx.x;
    int e = bid >> 5;
    int c0 = ((bid >> 1) & 15) * 64;   // h-col tile base
    int ypar = bid & 1;
    int n = cnt[e];
    int tid = threadIdx.x;

    __shared__ short Xs[64 * KC];      // [token][k] bf16, swizzled, 8 KB
    __shared__ short Ws[128 * KC];     // [wcol][k]: 0-63 gate, 64-127 up; 16 KB
    __shared__ int   tks[64];
    __shared__ int   rws[64];
    __shared__ float wts[64];

    const float* wbase = w13 + (size_t)e * HID * (2 * IDIM);

    // W staging role: 4 cols x 8 k per thread
    int c32 = tid & 31;                // col-group (4 cols of the 128)
    int kg  = tid >> 5;                // k-group (8 k)
    const float* wsrc = wbase + ((c32 < 16) ? (c0 + c32 * 4)
                                            : (IDIM + c0 + (c32 - 16) * 4));
    // X staging role
    int xrow = tid >> 2, xq = tid & 3;

    int wave = tid >> 6, lane = tid & 63;
    int lr = lane & 15, lh = lane >> 4;
    int swzA = (lr & 7) << 4;

    for (int t0 = ypar * 64; t0 < n; t0 += 128) {
        int nt = min(64, n - t0);
        __syncthreads();
        if (tid < 64) {
            int idx = t0 + min(tid, nt - 1);
            tks[tid] = tok[e * T_TOK + idx];
            rws[tid] = rowid[e * T_TOK + idx];
            wts[tid] = wt[e * T_TOK + idx];
        }
        __syncthreads();

        const float* xsrc = x + (size_t)tks[xrow] * HID + xq * 16;

        f32x4 accG[4], accU[4];
#pragma unroll
        for (int i = 0; i < 4; ++i) { accG[i] = (f32x4)0.f; accU[i] = (f32x4)0.f; }

        for (int kk = 0; kk < HID; kk += KC) {
            // ---- stage X tile (fp32 -> bf16) ----
#pragma unroll
            for (int f = 0; f < 2; ++f) {
                float4v a = *(const float4v*)(xsrc + kk + f * 8);
                float4v b = *(const float4v*)(xsrc + kk + f * 8 + 4);
                float tmp[8];
#pragma unroll
                for (int i = 0; i < 4; ++i) { tmp[i] = a[i]; tmp[4 + i] = b[i]; }
                int byte = (xrow * 128 + xq * 32 + f * 16) ^ ((xrow & 7) << 4);
                *(bf16x8*)((char*)Xs + byte) = pack8(tmp);
            }
            // ---- stage W tile: 8x float4 (4 cols x 8 k), transpose to [col][k] ----
            float4v wvv[8];
#pragma unroll
            for (int j = 0; j < 8; ++j)
                wvv[j] = *(const float4v*)(wsrc + (size_t)(kk + kg * 8 + j) * (2 * IDIM));
#pragma unroll
            for (int j2 = 0; j2 < 4; ++j2) {
                float tmp[8];
#pragma unroll
                for (int j = 0; j < 8; ++j) tmp[j] = wvv[j][j2];
                int col = c32 * 4 + j2;
                int byte = (col * 128 + kg * 16) ^ ((col & 7) << 4);
                *(bf16x8*)((char*)Ws + byte) = pack8(tmp);
            }
            __syncthreads();
            // ---- MFMA ----
#pragma unroll
            for (int s = 0; s < 2; ++s) {
                int kb = (s * 32 + lh * 8) * 2;
                bf16x8 a = *(const bf16x8*)((char*)Xs + (((wave * 16 + lr) * 128 + kb) ^ swzA));
#pragma unroll
                for (int cf = 0; cf < 4; ++cf) {
                    bf16x8 bg = *(const bf16x8*)((char*)Ws + (((cf * 16 + lr) * 128 + kb) ^ swzA));
                    accG[cf] = __builtin_amdgcn_mfma_f32_16x16x32_bf16(a, bg, accG[cf], 0, 0, 0);
                    bf16x8 bu = *(const bf16x8*)((char*)Ws + (((64 + cf * 16 + lr) * 128 + kb) ^ swzA));
                    accU[cf] = __builtin_amdgcn_mfma_f32_16x16x32_bf16(a, bu, accU[cf], 0, 0, 0);
                }
            }
            __syncthreads();
        }

        // ---- epilogue ----
#pragma unroll
        for (int cf = 0; cf < 4; ++cf) {
#pragma unroll
            for (int r = 0; r < 4; ++r) {
                int idx = wave * 16 + lh * 4 + r;
                if (idx < nt) {
                    float g = accG[cf][r], u = accU[cf][r];
                    float sg = g / (1.f + __expf(-g));
                    float v = wts[idx] * sg * u;
                    h[(size_t)rws[idx] * IDIM + c0 + cf * 16 + lr] = f2bf(v);
                }
            }
        }
    }
}

// ---------------- gemm2: out[t] += h[row] @ w2[e] ----------------
// 1-D grid of 512 blocks: e = bid>>5, x-tile(128 cols) = (bid>>1)&15, y-parity = bid&1.
__global__ __launch_bounds__(256) void gemm2_kernel(
    const unsigned short* __restrict__ h, const float* __restrict__ w2,
    const int* __restrict__ cnt, const int* __restrict__ tok,
    const int* __restrict__ rowid,
    float* __restrict__ out)
{
    int bid = blockIdx.x;
    int e = bid >> 5;
    int c0 = ((bid >> 1) & 15) * 128;
    int ypar = bid & 1;
    int n = cnt[e];
    int tid = threadIdx.x;

    __shared__ short Hs[64 * KC];
    __shared__ short Ws[128 * KC];
    __shared__ int   tks[64];
    __shared__ int   rws[64];

    const float* wbase = w2 + (size_t)e * IDIM * HID;

    int c32 = tid & 31;
    int kg  = tid >> 5;
    const float* wsrc = wbase + c0 + c32 * 4;
    int hrow = tid >> 2, hq = tid & 3;
    int hswz = (hrow & 7) << 4;

    int wave = tid >> 6, lane = tid & 63;
    int lr = lane & 15, lh = lane >> 4;
    int swzA = (lr & 7) << 4;

    for (int t0 = ypar * 64; t0 < n; t0 += 128) {
        int nt = min(64, n - t0);
        __syncthreads();
        if (tid < 64) {
            int idx = t0 + min(tid, nt - 1);
            tks[tid] = tok[e * T_TOK + idx];
            rws[tid] = rowid[e * T_TOK + idx];
        }
        __syncthreads();

        const unsigned short* hsrc = h + (size_t)rws[hrow] * IDIM + hq * 16;

        f32x4 acc[8];
#pragma unroll
        for (int i = 0; i < 8; ++i) acc[i] = (f32x4)0.f;

        for (int kk = 0; kk < IDIM; kk += KC) {
            // ---- stage H tile (bf16 direct) ----
            *(bf16x8*)((char*)Hs + ((hrow * 128 + hq * 32) ^ hswz)) =
                *(const bf16x8*)(hsrc + kk);
            *(bf16x8*)((char*)Hs + ((hrow * 128 + hq * 32 + 16) ^ hswz)) =
                *(const bf16x8*)(hsrc + kk + 8);
            // ---- stage W2 tile: 8x float4, transpose ----
            float4v wvv[8];
#pragma unroll
            for (int j = 0; j < 8; ++j)
                wvv[j] = *(const float4v*)(wsrc + (size_t)(kk + kg * 8 + j) * HID);
#pragma unroll
            for (int j2 = 0; j2 < 4; ++j2) {
                float tmp[8];
#pragma unroll
                for (int j = 0; j < 8; ++j) tmp[j] = wvv[j][j2];
                int col = c32 * 4 + j2;
                int byte = (col * 128 + kg * 16) ^ ((col & 7) << 4);
                *(bf16x8*)((char*)Ws + byte) = pack8(tmp);
            }
            __syncthreads();
            // ---- MFMA ----
#pragma unroll
            for (int s = 0; s < 2; ++s) {
                int kb = (s * 32 + lh * 8) * 2;
                bf16x8 a = *(const bf16x8*)((char*)Hs + (((wave * 16 + lr) * 128 + kb) ^ swzA));
#pragma unroll
                for (int cf = 0; cf < 8; ++cf) {
                    bf16x8 b = *(const bf16x8*)((char*)Ws + (((cf * 16 + lr) * 128 + kb) ^ swzA));
                    acc[cf] = __builtin_amdgcn_mfma_f32_16x16x32_bf16(a, b, acc[cf], 0, 0, 0);
                }
            }
            __syncthreads();
        }

#pragma unroll
        for (int cf = 0; cf < 8; ++cf) {
#pragma unroll
            for (int r = 0; r < 4; ++r) {
                int idx = wave * 16 + lh * 4 + r;
                if (idx < nt)
                    atomicAdd(&out[(size_t)tks[idx] * HID + c0 + cf * 16 + lr], acc[cf][r]);
            }
        }
    }
}

extern "C" void kernel_launch(void* const* d_in, const int* in_sizes, int n_in,
                              void* d_out, int out_size, void* d_ws, size_t ws_size,
                              hipStream_t stream) {
    const float* x   = (const float*)d_in[0];   // [T, H]
    const float* rw  = (const float*)d_in[1];   // [E, H]
    const float* w13 = (const float*)d_in[2];   // [E, H, 2I]
    const float* w2  = (const float*)d_in[3];   // [E, I, H]
    float* out = (float*)d_out;                 // [T, H]

    int* cnt   = (int*)d_ws;
    int* tok   = cnt + 64;
    int* rowid = tok + NEXP * T_TOK;
    float* wt  = (float*)(rowid + NEXP * T_TOK);
    unsigned short* h = (unsigned short*)((char*)d_ws + 131072); // [2T, I] bf16 = 2 MB

    hipMemsetAsync(out, 0, (size_t)T_TOK * HID * sizeof(float), stream);
    hipMemsetAsync(cnt, 0, 64 * sizeof(int), stream);

    router_kernel<<<T_TOK, 256, 0, stream>>>(x, rw, cnt, tok, rowid, wt);
    gemm1_kernel<<<512, 256, 0, stream>>>(x, w13, cnt, tok, rowid, wt, h);
    gemm2_kernel<<<512, 256, 0, stream>>>(h, w2, cnt, tok, rowid, out);
}

// Round 4
// 142.480 us; speedup vs baseline: 3.4571x; 1.2213x over previous
//
#include <hip/hip_runtime.h>

#define T_TOK 512
#define HID   2048
#define NEXP  16
#define IDIM  1024
#define KC    64

typedef __attribute__((ext_vector_type(8))) short bf16x8;
typedef __attribute__((ext_vector_type(4))) float f32x4;
typedef __attribute__((ext_vector_type(4))) float float4v;

__device__ __forceinline__ unsigned short f2bf(float f) {
    union { float f; unsigned u; } v; v.f = f;
    return (unsigned short)((v.u + 0x7FFFu + ((v.u >> 16) & 1u)) >> 16);
}

__device__ __forceinline__ bf16x8 pack8(const float* s) {
    bf16x8 r;
#pragma unroll
    for (int i = 0; i < 8; ++i) r[i] = (short)f2bf(s[i]);
    return r;
}

// ---------------- router ----------------
__global__ __launch_bounds__(256) void router_kernel(
    const float* __restrict__ x, const float* __restrict__ rw,
    int* __restrict__ cnt, int* __restrict__ tok,
    int* __restrict__ rowid, float* __restrict__ wt)
{
    int t = blockIdx.x;
    int tid = threadIdx.x;
    const float* xr = x + (size_t)t * HID;

    float acc[NEXP];
#pragma unroll
    for (int e = 0; e < NEXP; ++e) acc[e] = 0.f;

    for (int k = tid; k < HID; k += 256) {
        float xv = xr[k];
#pragma unroll
        for (int e = 0; e < NEXP; ++e) acc[e] += xv * rw[e * HID + k];
    }

    __shared__ float red[4][NEXP];
    int lane = tid & 63, wv = tid >> 6;
#pragma unroll
    for (int e = 0; e < NEXP; ++e) {
        float v = acc[e];
#pragma unroll
        for (int off = 32; off > 0; off >>= 1) v += __shfl_down(v, off);
        if (lane == 0) red[wv][e] = v;
    }
    __syncthreads();

    if (tid == 0) {
        float l[NEXP];
        float mx = -1e30f;
#pragma unroll
        for (int e = 0; e < NEXP; ++e) {
            l[e] = red[0][e] + red[1][e] + red[2][e] + red[3][e];
            mx = fmaxf(mx, l[e]);
        }
        float s = 0.f;
#pragma unroll
        for (int e = 0; e < NEXP; ++e) { l[e] = __expf(l[e] - mx); s += l[e]; }
        float inv_s = 1.f / s;
        int i0 = 0; float v0 = -1.f;
        int i1 = 0; float v1 = -2.f;
#pragma unroll
        for (int e = 0; e < NEXP; ++e) {
            float p = l[e] * inv_s;
            if (p > v0)      { v1 = v0; i1 = i0; v0 = p; i0 = e; }
            else if (p > v1) { v1 = p; i1 = e; }
        }
        float inv = 1.f / (v0 + v1);
        int p0 = atomicAdd(&cnt[i0], 1);
        tok[i0 * T_TOK + p0] = t; rowid[i0 * T_TOK + p0] = 2 * t;     wt[i0 * T_TOK + p0] = v0 * inv;
        int p1 = atomicAdd(&cnt[i1], 1);
        tok[i1 * T_TOK + p1] = t; rowid[i1 * T_TOK + p1] = 2 * t + 1; wt[i1 * T_TOK + p1] = v1 * inv;
    }
}

// ---- staging macros (roles: threads 0-255 stage W, 256-511 stage X/H) ----
#define LOADW(buf, kk_, stride_) { _Pragma("unroll") \
    for (int j = 0; j < 8; ++j) \
        buf[j] = *(const float4v*)(wsrc + (size_t)((kk_) + kg * 8 + j) * (stride_)); }

#define CVTW(buf) { _Pragma("unroll") \
    for (int j2 = 0; j2 < 4; ++j2) { \
        float tmp[8]; \
        _Pragma("unroll") for (int j = 0; j < 8; ++j) tmp[j] = buf[j][j2]; \
        int col = c32 * 4 + j2; \
        *(bf16x8*)((char*)Ws + ((col * 128 + kg * 16) ^ ((col & 7) << 4))) = pack8(tmp); } }

#define LOADX(buf, kk_) { _Pragma("unroll") \
    for (int f = 0; f < 8; ++f) buf[f] = *(const float4v*)(xsrc + (kk_) + f * 4); }

#define CVTX(buf) { _Pragma("unroll") \
    for (int f = 0; f < 4; ++f) { \
        float tmp[8]; \
        _Pragma("unroll") for (int i = 0; i < 4; ++i) { tmp[i] = buf[2*f][i]; tmp[4+i] = buf[2*f+1][i]; } \
        *(bf16x8*)((char*)Xs + ((xrow * 128 + xq * 64 + f * 16) ^ xswz)) = pack8(tmp); } }

#define LOADH(buf, kk_) { _Pragma("unroll") \
    for (int j = 0; j < 4; ++j) \
        buf[j] = *(const float4v*)((const char*)hsrc + (size_t)(kk_) * 2 + j * 16); }

#define CVTH(buf) { _Pragma("unroll") \
    for (int j = 0; j < 4; ++j) \
        *(float4v*)((char*)Xs + ((xrow * 128 + xq * 64 + j * 16) ^ xswz)) = buf[j]; }

// ---------------- gemm1: h[row] = wt * silu(x@Wg) * (x@Wu) ----------------
// 256 blocks: e = bid>>4, col-tile = bid&15 (64 gate + 64 up cols). M=128 tokens.
__global__ __launch_bounds__(512) void gemm1_kernel(
    const float* __restrict__ x, const float* __restrict__ w13,
    const int* __restrict__ cnt, const int* __restrict__ tok,
    const int* __restrict__ rowid, const float* __restrict__ wt,
    unsigned short* __restrict__ h)
{
    int bid = blockIdx.x;
    int e  = bid >> 4;
    int c0 = (bid & 15) * 64;
    int n = cnt[e];
    int tid = threadIdx.x;

    __shared__ short Xs[128 * KC];     // [token][k] bf16, swizzled, 16 KB
    __shared__ short Ws[128 * KC];     // [wcol][k]: 0-63 gate, 64-127 up; 16 KB
    __shared__ int   tks[128];
    __shared__ int   rws[128];
    __shared__ float wts[128];

    const float* wbase = w13 + (size_t)e * HID * (2 * IDIM);

    bool isW = tid < 256;
    int rtid = isW ? tid : (tid - 256);
    int c32 = rtid & 31, kg = rtid >> 5;                // W role: 4 cols x 8 k
    const float* wsrc = wbase + ((c32 < 16) ? (c0 + c32 * 4)
                                            : (IDIM + c0 + (c32 - 16) * 4));
    int xrow = rtid >> 1, xq = rtid & 1;                // X role: half-row of 32 k
    int xswz = (xrow & 7) << 4;

    int wave = tid >> 6, lane = tid & 63;
    int wm = wave & 3, wn = wave >> 2;                  // 4 M-strips x 2 N-halves
    int lr = lane & 15, lh = lane >> 4;
    int swzA = (lr & 7) << 4;

    for (int t0 = 0; t0 < n; t0 += 128) {
        int nt = min(128, n - t0);
        __syncthreads();
        if (tid < 128) {
            int idx = t0 + min(tid, nt - 1);
            tks[tid] = tok[e * T_TOK + idx];
            rws[tid] = rowid[e * T_TOK + idx];
            wts[tid] = wt[e * T_TOK + idx];
        }
        __syncthreads();

        const float* xsrc = x + (size_t)tks[xrow] * HID + xq * 32;

        f32x4 accG[2][2], accU[2][2];
#pragma unroll
        for (int i = 0; i < 2; ++i)
#pragma unroll
            for (int j = 0; j < 2; ++j) { accG[i][j] = (f32x4)0.f; accU[i][j] = (f32x4)0.f; }

        float4v bufA[8], bufB[8];
        if (isW) { LOADW(bufA, 0, 2 * IDIM); } else { LOADX(bufA, 0); }

#define G1_MFMA() { _Pragma("unroll") \
        for (int s = 0; s < 2; ++s) { \
            _Pragma("unroll") for (int mf = 0; mf < 2; ++mf) { \
                if (wm * 32 + mf * 16 < nt) { \
                    int kb = (s * 32 + lh * 8) * 2; \
                    bf16x8 a = *(const bf16x8*)((char*)Xs + (((wm*32 + mf*16 + lr) * 128 + kb) ^ swzA)); \
                    _Pragma("unroll") for (int cf = 0; cf < 2; ++cf) { \
                        int colg = wn * 32 + cf * 16 + lr; \
                        bf16x8 bg = *(const bf16x8*)((char*)Ws + ((colg * 128 + kb) ^ swzA)); \
                        accG[mf][cf] = __builtin_amdgcn_mfma_f32_16x16x32_bf16(a, bg, accG[mf][cf], 0, 0, 0); \
                        bf16x8 bu = *(const bf16x8*)((char*)Ws + (((64 + colg) * 128 + kb) ^ swzA)); \
                        accU[mf][cf] = __builtin_amdgcn_mfma_f32_16x16x32_bf16(a, bu, accU[mf][cf], 0, 0, 0); \
                    } \
                } \
            } \
        } }

        for (int kk = 0; kk < HID; kk += 2 * KC) {
            if (isW) { LOADW(bufB, kk + KC, 2 * IDIM); CVTW(bufA); }
            else     { LOADX(bufB, kk + KC);           CVTX(bufA); }
            __syncthreads();
            G1_MFMA();
            __syncthreads();
            if (kk + 2 * KC < HID) {
                if (isW) { LOADW(bufA, kk + 2 * KC, 2 * IDIM); } else { LOADX(bufA, kk + 2 * KC); }
            }
            if (isW) { CVTW(bufB); } else { CVTX(bufB); }
            __syncthreads();
            G1_MFMA();
            __syncthreads();
        }

        // epilogue: silu(g)*u * wt -> h (bf16)
#pragma unroll
        for (int mf = 0; mf < 2; ++mf)
#pragma unroll
            for (int cf = 0; cf < 2; ++cf)
#pragma unroll
                for (int r = 0; r < 4; ++r) {
                    int row = wm * 32 + mf * 16 + lh * 4 + r;
                    if (row < nt) {
                        float g = accG[mf][cf][r], u = accU[mf][cf][r];
                        float sg = g / (1.f + __expf(-g));
                        float v = wts[row] * sg * u;
                        h[(size_t)rws[row] * IDIM + c0 + wn * 32 + cf * 16 + lr] = f2bf(v);
                    }
                }
    }
}

// ---------------- gemm2: out[t] += h[row] @ w2[e] ----------------
// 256 blocks: e = bid>>4, col-tile = bid&15 (128 cols). M=128 rows.
__global__ __launch_bounds__(512) void gemm2_kernel(
    const unsigned short* __restrict__ h, const float* __restrict__ w2,
    const int* __restrict__ cnt, const int* __restrict__ tok,
    const int* __restrict__ rowid,
    float* __restrict__ out)
{
    int bid = blockIdx.x;
    int e  = bid >> 4;
    int c0 = (bid & 15) * 128;
    int n = cnt[e];
    int tid = threadIdx.x;

    __shared__ short Xs[128 * KC];     // H rows [row][k] bf16, swizzled
    __shared__ short Ws[128 * KC];     // W2 cols [col][k] bf16, swizzled
    __shared__ int   tks[128];
    __shared__ int   rws[128];

    const float* wbase = w2 + (size_t)e * IDIM * HID;

    bool isW = tid < 256;
    int rtid = isW ? tid : (tid - 256);
    int c32 = rtid & 31, kg = rtid >> 5;
    const float* wsrc = wbase + c0 + c32 * 4;
    int xrow = rtid >> 1, xq = rtid & 1;               // H role
    int xswz = (xrow & 7) << 4;

    int wave = tid >> 6, lane = tid & 63;
    int wm = wave & 3, wn = wave >> 2;
    int lr = lane & 15, lh = lane >> 4;
    int swzA = (lr & 7) << 4;

    for (int t0 = 0; t0 < n; t0 += 128) {
        int nt = min(128, n - t0);
        __syncthreads();
        if (tid < 128) {
            int idx = t0 + min(tid, nt - 1);
            tks[tid] = tok[e * T_TOK + idx];
            rws[tid] = rowid[e * T_TOK + idx];
        }
        __syncthreads();

        const unsigned short* hsrc = h + (size_t)rws[xrow] * IDIM + xq * 32;

        f32x4 acc[2][4];
#pragma unroll
        for (int i = 0; i < 2; ++i)
#pragma unroll
            for (int j = 0; j < 4; ++j) acc[i][j] = (f32x4)0.f;

        float4v bufA[8], bufB[8];
        if (isW) { LOADW(bufA, 0, HID); } else { LOADH(bufA, 0); }

#define G2_MFMA() { _Pragma("unroll") \
        for (int s = 0; s < 2; ++s) { \
            _Pragma("unroll") for (int mf = 0; mf < 2; ++mf) { \
                if (wm * 32 + mf * 16 < nt) { \
                    int kb = (s * 32 + lh * 8) * 2; \
                    bf16x8 a = *(const bf16x8*)((char*)Xs + (((wm*32 + mf*16 + lr) * 128 + kb) ^ swzA)); \
                    _Pragma("unroll") for (int cf = 0; cf < 4; ++cf) { \
                        int col = wn * 64 + cf * 16 + lr; \
                        bf16x8 b = *(const bf16x8*)((char*)Ws + ((col * 128 + kb) ^ swzA)); \
                        acc[mf][cf] = __builtin_amdgcn_mfma_f32_16x16x32_bf16(a, b, acc[mf][cf], 0, 0, 0); \
                    } \
                } \
            } \
        } }

        for (int kk = 0; kk < IDIM; kk += 2 * KC) {
            if (isW) { LOADW(bufB, kk + KC, HID); CVTW(bufA); }
            else     { LOADH(bufB, kk + KC);      CVTH(bufA); }
            __syncthreads();
            G2_MFMA();
            __syncthreads();
            if (kk + 2 * KC < IDIM) {
                if (isW) { LOADW(bufA, kk + 2 * KC, HID); } else { LOADH(bufA, kk + 2 * KC); }
            }
            if (isW) { CVTW(bufB); } else { CVTH(bufB); }
            __syncthreads();
            G2_MFMA();
            __syncthreads();
        }

#pragma unroll
        for (int mf = 0; mf < 2; ++mf)
#pragma unroll
            for (int cf = 0; cf < 4; ++cf)
#pragma unroll
                for (int r = 0; r < 4; ++r) {
                    int row = wm * 32 + mf * 16 + lh * 4 + r;
                    if (row < nt)
                        atomicAdd(&out[(size_t)tks[row] * HID + c0 + wn * 64 + cf * 16 + lr],
                                  acc[mf][cf][r]);
                }
    }
}

extern "C" void kernel_launch(void* const* d_in, const int* in_sizes, int n_in,
                              void* d_out, int out_size, void* d_ws, size_t ws_size,
                              hipStream_t stream) {
    const float* x   = (const float*)d_in[0];   // [T, H]
    const float* rw  = (const float*)d_in[1];   // [E, H]
    const float* w13 = (const float*)d_in[2];   // [E, H, 2I]
    const float* w2  = (const float*)d_in[3];   // [E, I, H]
    float* out = (float*)d_out;                 // [T, H]

    int* cnt   = (int*)d_ws;
    int* tok   = cnt + 64;
    int* rowid = tok + NEXP * T_TOK;
    float* wt  = (float*)(rowid + NEXP * T_TOK);
    unsigned short* h = (unsigned short*)((char*)d_ws + 131072); // [2T, I] bf16 = 2 MB

    hipMemsetAsync(out, 0, (size_t)T_TOK * HID * sizeof(float), stream);
    hipMemsetAsync(cnt, 0, 64 * sizeof(int), stream);

    router_kernel<<<T_TOK, 256, 0, stream>>>(x, rw, cnt, tok, rowid, wt);
    gemm1_kernel<<<256, 512, 0, stream>>>(x, w13, cnt, tok, rowid, wt, h);
    gemm2_kernel<<<256, 512, 0, stream>>>(h, w2, cnt, tok, rowid, out);
}

// Round 5
// 133.175 us; speedup vs baseline: 3.6986x; 1.0699x over previous
//
#include <hip/hip_runtime.h>

#define T_TOK 512
#define HID   2048
#define NEXP  16
#define IDIM  1024
#define KC    64

typedef __attribute__((ext_vector_type(8))) short bf16x8;
typedef __attribute__((ext_vector_type(4))) float f32x4;
typedef __attribute__((ext_vector_type(4))) float float4v;

__device__ __forceinline__ unsigned short f2bf(float f) {
    union { float f; unsigned u; } v; v.f = f;
    return (unsigned short)((v.u + 0x7FFFu + ((v.u >> 16) & 1u)) >> 16);
}

__device__ __forceinline__ unsigned pack2(float lo, float hi) {
    return (unsigned)f2bf(lo) | ((unsigned)f2bf(hi) << 16);
}

__device__ __forceinline__ bf16x8 pack8(const float* s) {
    bf16x8 r;
#pragma unroll
    for (int i = 0; i < 8; ++i) r[i] = (short)f2bf(s[i]);
    return r;
}

// ---------------- router (+ x -> bf16 conversion) ----------------
__global__ __launch_bounds__(256) void router_kernel(
    const float* __restrict__ x, const float* __restrict__ rw,
    int* __restrict__ cnt, int* __restrict__ tok,
    int* __restrict__ rowid, float* __restrict__ wt,
    unsigned short* __restrict__ xb)
{
    int t = blockIdx.x;
    int tid = threadIdx.x;
    const float* xr = x + (size_t)t * HID;

    // x -> bf16 (8 elems/thread)
    {
        int c = tid * 8;
        float4v a = *(const float4v*)(xr + c);
        float4v b = *(const float4v*)(xr + c + 4);
        float tmp[8];
#pragma unroll
        for (int i = 0; i < 4; ++i) { tmp[i] = a[i]; tmp[4 + i] = b[i]; }
        *(bf16x8*)(xb + (size_t)t * HID + c) = pack8(tmp);
    }

    float acc[NEXP];
#pragma unroll
    for (int e = 0; e < NEXP; ++e) acc[e] = 0.f;

    for (int k = tid; k < HID; k += 256) {
        float xv = xr[k];
#pragma unroll
        for (int e = 0; e < NEXP; ++e) acc[e] += xv * rw[e * HID + k];
    }

    __shared__ float red[4][NEXP];
    int lane = tid & 63, wv = tid >> 6;
#pragma unroll
    for (int e = 0; e < NEXP; ++e) {
        float v = acc[e];
#pragma unroll
        for (int off = 32; off > 0; off >>= 1) v += __shfl_down(v, off);
        if (lane == 0) red[wv][e] = v;
    }
    __syncthreads();

    if (tid == 0) {
        float l[NEXP];
        float mx = -1e30f;
#pragma unroll
        for (int e = 0; e < NEXP; ++e) {
            l[e] = red[0][e] + red[1][e] + red[2][e] + red[3][e];
            mx = fmaxf(mx, l[e]);
        }
        float s = 0.f;
#pragma unroll
        for (int e = 0; e < NEXP; ++e) { l[e] = __expf(l[e] - mx); s += l[e]; }
        float inv_s = 1.f / s;
        int i0 = 0; float v0 = -1.f;
        int i1 = 0; float v1 = -2.f;
#pragma unroll
        for (int e = 0; e < NEXP; ++e) {
            float p = l[e] * inv_s;
            if (p > v0)      { v1 = v0; i1 = i0; v0 = p; i0 = e; }
            else if (p > v1) { v1 = p; i1 = e; }
        }
        float inv = 1.f / (v0 + v1);
        int p0 = atomicAdd(&cnt[i0], 1);
        tok[i0 * T_TOK + p0] = t; rowid[i0 * T_TOK + p0] = 2 * t;     wt[i0 * T_TOK + p0] = v0 * inv;
        int p1 = atomicAdd(&cnt[i1], 1);
        tok[i1 * T_TOK + p1] = t; rowid[i1 * T_TOK + p1] = 2 * t + 1; wt[i1 * T_TOK + p1] = v1 * inv;
    }
}

// ---- staging macros: all 512 threads stage both tiles ----
// W role: cg = tid&15 (4 cols), kg = tid>>4 (k-pair kg*2)
#define LOADW(buf, kk_, stride_) { \
    buf[0] = *(const float4v*)(wsrc + (size_t)((kk_) + kg * 2)     * (stride_)); \
    buf[1] = *(const float4v*)(wsrc + (size_t)((kk_) + kg * 2 + 1) * (stride_)); }

#define STOREW(buf) { _Pragma("unroll") \
    for (int j2 = 0; j2 < 4; ++j2) { \
        int colw = cg * 4 + j2; \
        *(unsigned*)((char*)Ws + ((colw * 128 + kg * 4) ^ ((colw & 7) << 4))) = \
            pack2(buf[0][j2], buf[1][j2]); } }

// X/H role: xrow = tid>>2, xq = tid&3 (32B of the 128B bf16 row-slice)
#define LOADX(buf, kk_) { \
    buf[0] = *(const bf16x8*)(xsrc + (kk_)); \
    buf[1] = *(const bf16x8*)(xsrc + (kk_) + 8); }

#define STOREX(buf) { \
    *(bf16x8*)((char*)Xs + ((xrow * 128 + xq * 32)      ^ xswz)) = buf[0]; \
    *(bf16x8*)((char*)Xs + ((xrow * 128 + xq * 32 + 16) ^ xswz)) = buf[1]; }

// ---------------- gemm1: h[row] = wt * silu(x@Wg) * (x@Wu) ----------------
// 512 blocks: e = bid>>5, col-tile = bid&31 (32 h-cols). M=128 tokens. 2 blocks/CU.
__global__ __launch_bounds__(512, 4) void gemm1_kernel(
    const unsigned short* __restrict__ xb, const float* __restrict__ w13,
    const int* __restrict__ cnt, const int* __restrict__ tok,
    const int* __restrict__ rowid, const float* __restrict__ wt,
    unsigned short* __restrict__ h)
{
    int bid = blockIdx.x;
    int e  = bid >> 5;
    int c0 = (bid & 31) * 32;          // h-col tile base
    int n = cnt[e];
    int tid = threadIdx.x;

    __shared__ __align__(16) short Xs[128 * KC];   // 16 KB
    __shared__ __align__(16) short Ws[64 * KC];    // 8 KB: rows 0-31 gate, 32-63 up
    __shared__ int   tks[128];
    __shared__ int   rws[128];
    __shared__ float wts[128];

    const float* wbase = w13 + (size_t)e * HID * (2 * IDIM);

    int cg = tid & 15, kg = tid >> 4;
    const float* wsrc = wbase + ((cg < 8) ? (c0 + cg * 4)
                                          : (IDIM + c0 + (cg - 8) * 4));
    int xrow = tid >> 2, xq = tid & 3;
    int xswz = (xrow & 7) << 4;

    int wave = tid >> 6, lane = tid & 63;
    int lr = lane & 15, lh = lane >> 4;
    int swzA = (lr & 7) << 4;

    for (int t0 = 0; t0 < n; t0 += 128) {
        int nt = min(128, n - t0);
        __syncthreads();
        if (tid < 128) {
            int idx = t0 + min(tid, nt - 1);
            tks[tid] = tok[e * T_TOK + idx];
            rws[tid] = rowid[e * T_TOK + idx];
            wts[tid] = wt[e * T_TOK + idx];
        }
        __syncthreads();

        const unsigned short* xsrc = xb + (size_t)tks[xrow] * HID + xq * 16;

        f32x4 accG[2], accU[2];
#pragma unroll
        for (int i = 0; i < 2; ++i) { accG[i] = (f32x4)0.f; accU[i] = (f32x4)0.f; }

        float4v wbufA[2], wbufB[2];
        bf16x8 xbufA[2], xbufB[2];
        LOADW(wbufA, 0, 2 * IDIM); LOADX(xbufA, 0);

#define G1_MFMA() { \
        if (wave * 16 < nt) { _Pragma("unroll") \
            for (int s = 0; s < 2; ++s) { \
                int kb = (s * 32 + lh * 8) * 2; \
                bf16x8 a = *(const bf16x8*)((char*)Xs + (((wave * 16 + lr) * 128 + kb) ^ swzA)); \
                _Pragma("unroll") for (int cf = 0; cf < 2; ++cf) { \
                    int colg = cf * 16 + lr; \
                    bf16x8 bg = *(const bf16x8*)((char*)Ws + ((colg * 128 + kb) ^ swzA)); \
                    accG[cf] = __builtin_amdgcn_mfma_f32_16x16x32_bf16(a, bg, accG[cf], 0, 0, 0); \
                    bf16x8 bu = *(const bf16x8*)((char*)Ws + (((32 + colg) * 128 + kb) ^ swzA)); \
                    accU[cf] = __builtin_amdgcn_mfma_f32_16x16x32_bf16(a, bu, accU[cf], 0, 0, 0); \
                } \
            } \
        } }

        for (int kk = 0; kk < HID; kk += 2 * KC) {
            LOADW(wbufB, kk + KC, 2 * IDIM); LOADX(xbufB, kk + KC);
            STOREW(wbufA); STOREX(xbufA);
            __syncthreads();
            G1_MFMA();
            __syncthreads();
            if (kk + 2 * KC < HID) { LOADW(wbufA, kk + 2 * KC, 2 * IDIM); LOADX(xbufA, kk + 2 * KC); }
            STOREW(wbufB); STOREX(xbufB);
            __syncthreads();
            G1_MFMA();
            __syncthreads();
        }

        // epilogue: silu(g)*u * wt -> h (bf16)
#pragma unroll
        for (int cf = 0; cf < 2; ++cf)
#pragma unroll
            for (int r = 0; r < 4; ++r) {
                int row = wave * 16 + lh * 4 + r;
                if (row < nt) {
                    float g = accG[cf][r], u = accU[cf][r];
                    float sg = g / (1.f + __expf(-g));
                    float v = wts[row] * sg * u;
                    h[(size_t)rws[row] * IDIM + c0 + cf * 16 + lr] = f2bf(v);
                }
            }
    }
}

// ---------------- gemm2: out[t] += h[row] @ w2[e] ----------------
// 512 blocks: e = bid>>5, col-tile = bid&31 (64 out-cols). M=128 rows. 2 blocks/CU.
__global__ __launch_bounds__(512, 4) void gemm2_kernel(
    const unsigned short* __restrict__ h, const float* __restrict__ w2,
    const int* __restrict__ cnt, const int* __restrict__ tok,
    const int* __restrict__ rowid,
    float* __restrict__ out)
{
    int bid = blockIdx.x;
    int e  = bid >> 5;
    int c0 = (bid & 31) * 64;
    int n = cnt[e];
    int tid = threadIdx.x;

    __shared__ __align__(16) short Xs[128 * KC];   // H rows, 16 KB
    __shared__ __align__(16) short Ws[64 * KC];    // W2 cols, 8 KB
    __shared__ int   tks[128];
    __shared__ int   rws[128];

    const float* wbase = w2 + (size_t)e * IDIM * HID;

    int cg = tid & 15, kg = tid >> 4;
    const float* wsrc = wbase + c0 + cg * 4;
    int xrow = tid >> 2, xq = tid & 3;
    int xswz = (xrow & 7) << 4;

    int wave = tid >> 6, lane = tid & 63;
    int lr = lane & 15, lh = lane >> 4;
    int swzA = (lr & 7) << 4;

    for (int t0 = 0; t0 < n; t0 += 128) {
        int nt = min(128, n - t0);
        __syncthreads();
        if (tid < 128) {
            int idx = t0 + min(tid, nt - 1);
            tks[tid] = tok[e * T_TOK + idx];
            rws[tid] = rowid[e * T_TOK + idx];
        }
        __syncthreads();

        const unsigned short* xsrc = h + (size_t)rws[xrow] * IDIM + xq * 16;

        f32x4 acc[4];
#pragma unroll
        for (int i = 0; i < 4; ++i) acc[i] = (f32x4)0.f;

        float4v wbufA[2], wbufB[2];
        bf16x8 xbufA[2], xbufB[2];
        LOADW(wbufA, 0, HID); LOADX(xbufA, 0);

#define G2_MFMA() { \
        if (wave * 16 < nt) { _Pragma("unroll") \
            for (int s = 0; s < 2; ++s) { \
                int kb = (s * 32 + lh * 8) * 2; \
                bf16x8 a = *(const bf16x8*)((char*)Xs + (((wave * 16 + lr) * 128 + kb) ^ swzA)); \
                _Pragma("unroll") for (int cf = 0; cf < 4; ++cf) { \
                    int col = cf * 16 + lr; \
                    bf16x8 b = *(const bf16x8*)((char*)Ws + ((col * 128 + kb) ^ swzA)); \
                    acc[cf] = __builtin_amdgcn_mfma_f32_16x16x32_bf16(a, b, acc[cf], 0, 0, 0); \
                } \
            } \
        } }

        for (int kk = 0; kk < IDIM; kk += 2 * KC) {
            LOADW(wbufB, kk + KC, HID); LOADX(xbufB, kk + KC);
            STOREW(wbufA); STOREX(xbufA);
            __syncthreads();
            G2_MFMA();
            __syncthreads();
            if (kk + 2 * KC < IDIM) { LOADW(wbufA, kk + 2 * KC, HID); LOADX(xbufA, kk + 2 * KC); }
            STOREW(wbufB); STOREX(xbufB);
            __syncthreads();
            G2_MFMA();
            __syncthreads();
        }

#pragma unroll
        for (int cf = 0; cf < 4; ++cf)
#pragma unroll
            for (int r = 0; r < 4; ++r) {
                int row = wave * 16 + lh * 4 + r;
                if (row < nt)
                    atomicAdd(&out[(size_t)tks[row] * HID + c0 + cf * 16 + lr], acc[cf][r]);
            }
    }
}

extern "C" void kernel_launch(void* const* d_in, const int* in_sizes, int n_in,
                              void* d_out, int out_size, void* d_ws, size_t ws_size,
                              hipStream_t stream) {
    const float* x   = (const float*)d_in[0];   // [T, H]
    const float* rw  = (const float*)d_in[1];   // [E, H]
    const float* w13 = (const float*)d_in[2];   // [E, H, 2I]
    const float* w2  = (const float*)d_in[3];   // [E, I, H]
    float* out = (float*)d_out;                 // [T, H]

    int* cnt   = (int*)d_ws;
    int* tok   = cnt + 64;
    int* rowid = tok + NEXP * T_TOK;
    float* wt  = (float*)(rowid + NEXP * T_TOK);
    unsigned short* h  = (unsigned short*)((char*)d_ws + 131072);           // [2T, I] bf16 = 2 MB
    unsigned short* xb = (unsigned short*)((char*)d_ws + 131072 + 2097152); // [T, H] bf16 = 2 MB

    hipMemsetAsync(out, 0, (size_t)T_TOK * HID * sizeof(float), stream);
    hipMemsetAsync(cnt, 0, 64 * sizeof(int), stream);

    router_kernel<<<T_TOK, 256, 0, stream>>>(x, rw, cnt, tok, rowid, wt, xb);
    gemm1_kernel<<<512, 512, 0, stream>>>(xb, w13, cnt, tok, rowid, wt, h);
    gemm2_kernel<<<512, 512, 0, stream>>>(h, w2, cnt, tok, rowid, out);
}

// Round 6
// 132.933 us; speedup vs baseline: 3.7054x; 1.0018x over previous
//
#include <hip/hip_runtime.h>

#define T_TOK 512
#define HID   2048
#define NEXP  16
#define IDIM  1024
#define KC    64

typedef __attribute__((ext_vector_type(8))) short bf16x8;
typedef __attribute__((ext_vector_type(4))) float f32x4;
typedef __attribute__((ext_vector_type(4))) float float4v;

__device__ __forceinline__ unsigned short f2bf(float f) {
    union { float f; unsigned u; } v; v.f = f;
    return (unsigned short)((v.u + 0x7FFFu + ((v.u >> 16) & 1u)) >> 16);
}

__device__ __forceinline__ unsigned pack2(float lo, float hi) {
    return (unsigned)f2bf(lo) | ((unsigned)f2bf(hi) << 16);
}

__device__ __forceinline__ bf16x8 pack8(const float* s) {
    bf16x8 r;
#pragma unroll
    for (int i = 0; i < 8; ++i) r[i] = (short)f2bf(s[i]);
    return r;
}

// ---------------- router (+ x -> bf16 conversion) ----------------
__global__ __launch_bounds__(256) void router_kernel(
    const float* __restrict__ x, const float* __restrict__ rw,
    int* __restrict__ cnt, int* __restrict__ tok,
    int* __restrict__ rowid, float* __restrict__ wt,
    unsigned short* __restrict__ xb)
{
    int t = blockIdx.x;
    int tid = threadIdx.x;
    const float* xr = x + (size_t)t * HID;

    {
        int c = tid * 8;
        float4v a = *(const float4v*)(xr + c);
        float4v b = *(const float4v*)(xr + c + 4);
        float tmp[8];
#pragma unroll
        for (int i = 0; i < 4; ++i) { tmp[i] = a[i]; tmp[4 + i] = b[i]; }
        *(bf16x8*)(xb + (size_t)t * HID + c) = pack8(tmp);
    }

    float acc[NEXP];
#pragma unroll
    for (int e = 0; e < NEXP; ++e) acc[e] = 0.f;

    for (int k = tid; k < HID; k += 256) {
        float xv = xr[k];
#pragma unroll
        for (int e = 0; e < NEXP; ++e) acc[e] += xv * rw[e * HID + k];
    }

    __shared__ float red[4][NEXP];
    int lane = tid & 63, wv = tid >> 6;
#pragma unroll
    for (int e = 0; e < NEXP; ++e) {
        float v = acc[e];
#pragma unroll
        for (int off = 32; off > 0; off >>= 1) v += __shfl_down(v, off);
        if (lane == 0) red[wv][e] = v;
    }
    __syncthreads();

    if (tid == 0) {
        float l[NEXP];
        float mx = -1e30f;
#pragma unroll
        for (int e = 0; e < NEXP; ++e) {
            l[e] = red[0][e] + red[1][e] + red[2][e] + red[3][e];
            mx = fmaxf(mx, l[e]);
        }
        float s = 0.f;
#pragma unroll
        for (int e = 0; e < NEXP; ++e) { l[e] = __expf(l[e] - mx); s += l[e]; }
        float inv_s = 1.f / s;
        int i0 = 0; float v0 = -1.f;
        int i1 = 0; float v1 = -2.f;
#pragma unroll
        for (int e = 0; e < NEXP; ++e) {
            float p = l[e] * inv_s;
            if (p > v0)      { v1 = v0; i1 = i0; v0 = p; i0 = e; }
            else if (p > v1) { v1 = p; i1 = e; }
        }
        float inv = 1.f / (v0 + v1);
        int p0 = atomicAdd(&cnt[i0], 1);
        tok[i0 * T_TOK + p0] = t; rowid[i0 * T_TOK + p0] = 2 * t;     wt[i0 * T_TOK + p0] = v0 * inv;
        int p1 = atomicAdd(&cnt[i1], 1);
        tok[i1 * T_TOK + p1] = t; rowid[i1 * T_TOK + p1] = 2 * t + 1; wt[i1 * T_TOK + p1] = v1 * inv;
    }
}

// ---- staging macros ----
// W role: cg = tid&15 (4 cols), kg = tid>>4 (k-pair kg*2)
#define LOADW(buf, kk_, stride_) { \
    buf[0] = *(const float4v*)(wsrc + (size_t)((kk_) + kg * 2)     * (stride_)); \
    buf[1] = *(const float4v*)(wsrc + (size_t)((kk_) + kg * 2 + 1) * (stride_)); }

#define STOREW(buf, Wd) { _Pragma("unroll") \
    for (int j2 = 0; j2 < 4; ++j2) { \
        int colw = cg * 4 + j2; \
        *(unsigned*)((char*)(Wd) + ((colw * 128 + kg * 4) ^ ((colw & 7) << 4))) = \
            pack2(buf[0][j2], buf[1][j2]); } }

// X/H role: xrow = tid>>2, xq = tid&3
#define LOADX(buf, kk_) { \
    buf[0] = *(const bf16x8*)(xsrc + (kk_)); \
    buf[1] = *(const bf16x8*)(xsrc + (kk_) + 8); }

#define STOREX(buf, Xd) { \
    *(bf16x8*)((char*)(Xd) + ((xrow * 128 + xq * 32)      ^ xswz)) = buf[0]; \
    *(bf16x8*)((char*)(Xd) + ((xrow * 128 + xq * 32 + 16) ^ xswz)) = buf[1]; }

// ---------------- gemm1: h[row] = wt * silu(x@Wg) * (x@Wu) ----------------
// 512 blocks: e = bid>>5, col-tile = bid&31 (32 h-cols). M=128 tokens. 2 blocks/CU.
__global__ __launch_bounds__(512, 4) void gemm1_kernel(
    const unsigned short* __restrict__ xb, const float* __restrict__ w13,
    const int* __restrict__ cnt, const int* __restrict__ tok,
    const int* __restrict__ rowid, const float* __restrict__ wt,
    unsigned short* __restrict__ h)
{
    int bid = blockIdx.x;
    int e  = bid >> 5;
    int c0 = (bid & 31) * 32;
    int n = cnt[e];
    int tid = threadIdx.x;

    __shared__ __align__(16) short Xs[2][128 * KC];   // 2 x 16 KB
    __shared__ __align__(16) short Ws[2][64 * KC];    // 2 x 8 KB (0-31 gate, 32-63 up)
    __shared__ int   tks[128];
    __shared__ int   rws[128];
    __shared__ float wts[128];

    const float* wbase = w13 + (size_t)e * HID * (2 * IDIM);

    int cg = tid & 15, kg = tid >> 4;
    const float* wsrc = wbase + ((cg < 8) ? (c0 + cg * 4)
                                          : (IDIM + c0 + (cg - 8) * 4));
    int xrow = tid >> 2, xq = tid & 3;
    int xswz = (xrow & 7) << 4;

    int wave = tid >> 6, lane = tid & 63;
    int lr = lane & 15, lh = lane >> 4;
    int swzA = (lr & 7) << 4;

#define G1_MFMA(Xd, Wd) { if (wave * 16 < nt) { _Pragma("unroll") \
    for (int s = 0; s < 2; ++s) { \
        int kb = (s * 32 + lh * 8) * 2; \
        bf16x8 a = *(const bf16x8*)((char*)(Xd) + (((wave * 16 + lr) * 128 + kb) ^ swzA)); \
        _Pragma("unroll") for (int cf = 0; cf < 2; ++cf) { \
            int colg = cf * 16 + lr; \
            bf16x8 bg = *(const bf16x8*)((char*)(Wd) + ((colg * 128 + kb) ^ swzA)); \
            accG[cf] = __builtin_amdgcn_mfma_f32_16x16x32_bf16(a, bg, accG[cf], 0, 0, 0); \
            bf16x8 bu = *(const bf16x8*)((char*)(Wd) + (((32 + colg) * 128 + kb) ^ swzA)); \
            accU[cf] = __builtin_amdgcn_mfma_f32_16x16x32_bf16(a, bu, accU[cf], 0, 0, 0); \
        } } } }

    for (int t0 = 0; t0 < n; t0 += 128) {
        int nt = min(128, n - t0);
        __syncthreads();
        if (tid < 128) {
            int idx = t0 + min(tid, nt - 1);
            tks[tid] = tok[e * T_TOK + idx];
            rws[tid] = rowid[e * T_TOK + idx];
            wts[tid] = wt[e * T_TOK + idx];
        }
        __syncthreads();

        const unsigned short* xsrc = xb + (size_t)tks[xrow] * HID + xq * 16;

        f32x4 accG[2], accU[2];
#pragma unroll
        for (int i = 0; i < 2; ++i) { accG[i] = (f32x4)0.f; accU[i] = (f32x4)0.f; }

        float4v rWa[2], rWb[2];
        bf16x8 rXa[2], rXb[2];
        LOADW(rWa, 0, 2 * IDIM);  LOADX(rXa, 0);
        LOADW(rWb, KC, 2 * IDIM); LOADX(rXb, KC);
        STOREW(rWa, Ws[0]); STOREX(rXa, Xs[0]);
        __syncthreads();

        for (int p = 0; p < HID / KC; p += 2) {
            int kf0 = (p + 2) * KC, kf1 = (p + 3) * KC;
            if (kf0 < HID) { LOADW(rWa, kf0, 2 * IDIM); LOADX(rXa, kf0); }
            G1_MFMA(Xs[0], Ws[0]);
            STOREW(rWb, Ws[1]); STOREX(rXb, Xs[1]);
            __syncthreads();
            if (kf1 < HID) { LOADW(rWb, kf1, 2 * IDIM); LOADX(rXb, kf1); }
            G1_MFMA(Xs[1], Ws[1]);
            if (kf0 < HID) { STOREW(rWa, Ws[0]); STOREX(rXa, Xs[0]); }
            __syncthreads();
        }

        // epilogue: silu(g)*u * wt -> h (bf16)
#pragma unroll
        for (int cf = 0; cf < 2; ++cf)
#pragma unroll
            for (int r = 0; r < 4; ++r) {
                int row = wave * 16 + lh * 4 + r;
                if (row < nt) {
                    float g = accG[cf][r], u = accU[cf][r];
                    float sg = g / (1.f + __expf(-g));
                    float v = wts[row] * sg * u;
                    h[(size_t)rws[row] * IDIM + c0 + cf * 16 + lr] = f2bf(v);
                }
            }
    }
}

// ---------------- gemm2: out[t] += h[row] @ w2[e] ----------------
// 512 blocks: e = bid>>5, col-tile = bid&31 (64 out-cols). M=128 rows. 2 blocks/CU.
__global__ __launch_bounds__(512, 4) void gemm2_kernel(
    const unsigned short* __restrict__ h, const float* __restrict__ w2,
    const int* __restrict__ cnt, const int* __restrict__ tok,
    const int* __restrict__ rowid,
    float* __restrict__ out)
{
    int bid = blockIdx.x;
    int e  = bid >> 5;
    int c0 = (bid & 31) * 64;
    int n = cnt[e];
    int tid = threadIdx.x;

    __shared__ __align__(16) short Xs[2][128 * KC];
    __shared__ __align__(16) short Ws[2][64 * KC];
    __shared__ int   tks[128];
    __shared__ int   rws[128];

    const float* wbase = w2 + (size_t)e * IDIM * HID;

    int cg = tid & 15, kg = tid >> 4;
    const float* wsrc = wbase + c0 + cg * 4;
    int xrow = tid >> 2, xq = tid & 3;
    int xswz = (xrow & 7) << 4;

    int wave = tid >> 6, lane = tid & 63;
    int lr = lane & 15, lh = lane >> 4;
    int swzA = (lr & 7) << 4;

#define G2_MFMA(Xd, Wd) { if (wave * 16 < nt) { _Pragma("unroll") \
    for (int s = 0; s < 2; ++s) { \
        int kb = (s * 32 + lh * 8) * 2; \
        bf16x8 a = *(const bf16x8*)((char*)(Xd) + (((wave * 16 + lr) * 128 + kb) ^ swzA)); \
        _Pragma("unroll") for (int cf = 0; cf < 4; ++cf) { \
            int col = cf * 16 + lr; \
            bf16x8 b = *(const bf16x8*)((char*)(Wd) + ((col * 128 + kb) ^ swzA)); \
            acc[cf] = __builtin_amdgcn_mfma_f32_16x16x32_bf16(a, b, acc[cf], 0, 0, 0); \
        } } } }

    for (int t0 = 0; t0 < n; t0 += 128) {
        int nt = min(128, n - t0);
        __syncthreads();
        if (tid < 128) {
            int idx = t0 + min(tid, nt - 1);
            tks[tid] = tok[e * T_TOK + idx];
            rws[tid] = rowid[e * T_TOK + idx];
        }
        __syncthreads();

        const unsigned short* xsrc = h + (size_t)rws[xrow] * IDIM + xq * 16;

        f32x4 acc[4];
#pragma unroll
        for (int i = 0; i < 4; ++i) acc[i] = (f32x4)0.f;

        float4v rWa[2], rWb[2];
        bf16x8 rXa[2], rXb[2];
        LOADW(rWa, 0, HID);  LOADX(rXa, 0);
        LOADW(rWb, KC, HID); LOADX(rXb, KC);
        STOREW(rWa, Ws[0]); STOREX(rXa, Xs[0]);
        __syncthreads();

        for (int p = 0; p < IDIM / KC; p += 2) {
            int kf0 = (p + 2) * KC, kf1 = (p + 3) * KC;
            if (kf0 < IDIM) { LOADW(rWa, kf0, HID); LOADX(rXa, kf0); }
            G2_MFMA(Xs[0], Ws[0]);
            STOREW(rWb, Ws[1]); STOREX(rXb, Xs[1]);
            __syncthreads();
            if (kf1 < IDIM) { LOADW(rWb, kf1, HID); LOADX(rXb, kf1); }
            G2_MFMA(Xs[1], Ws[1]);
            if (kf0 < IDIM) { STOREW(rWa, Ws[0]); STOREX(rXa, Xs[0]); }
            __syncthreads();
        }

#pragma unroll
        for (int cf = 0; cf < 4; ++cf)
#pragma unroll
            for (int r = 0; r < 4; ++r) {
                int row = wave * 16 + lh * 4 + r;
                if (row < nt)
                    atomicAdd(&out[(size_t)tks[row] * HID + c0 + cf * 16 + lr], acc[cf][r]);
            }
    }
}

extern "C" void kernel_launch(void* const* d_in, const int* in_sizes, int n_in,
                              void* d_out, int out_size, void* d_ws, size_t ws_size,
                              hipStream_t stream) {
    const float* x   = (const float*)d_in[0];   // [T, H]
    const float* rw  = (const float*)d_in[1];   // [E, H]
    const float* w13 = (const float*)d_in[2];   // [E, H, 2I]
    const float* w2  = (const float*)d_in[3];   // [E, I, H]
    float* out = (float*)d_out;                 // [T, H]

    int* cnt   = (int*)d_ws;
    int* tok   = cnt + 64;
    int* rowid = tok + NEXP * T_TOK;
    float* wt  = (float*)(rowid + NEXP * T_TOK);
    unsigned short* h  = (unsigned short*)((char*)d_ws + 131072);           // [2T, I] bf16
    unsigned short* xb = (unsigned short*)((char*)d_ws + 131072 + 2097152); // [T, H] bf16

    hipMemsetAsync(out, 0, (size_t)T_TOK * HID * sizeof(float), stream);
    hipMemsetAsync(cnt, 0, 64 * sizeof(int), stream);

    router_kernel<<<T_TOK, 256, 0, stream>>>(x, rw, cnt, tok, rowid, wt, xb);
    gemm1_kernel<<<512, 512, 0, stream>>>(xb, w13, cnt, tok, rowid, wt, h);
    gemm2_kernel<<<512, 512, 0, stream>>>(h, w2, cnt, tok, rowid, out);
}